// Round 4
// baseline (275.221 us; speedup 1.0000x reference)
//
#include <hip/hip_runtime.h>

// ROIAlign forward (PH=PW=7, SCALE=0.25, SR=2, ALIGNED=true)
//   input [4,256,200,200] fp32 NCHW, rois [512,5], out [512,256,7,7] fp32
//
// Round-4: strip-LDS gather + fully precomputed sample metadata.
//   - R3 showed kernel-sum 93us (vs 138 baseline); residual = per-item VALU
//     recompute (~100 ops repeated per channel), 3 blocks/CU occupancy, and
//     16 scalar LDS taps.
//   - Pre-kernel now stores per-(n,ph): 4 row offsets (premult x200) + 4
//     y-weights (x0.25 folded), per-(n,pw): 4 cols + 4 x-weights. The 16-tap
//     bilinear sum is exactly the 4x4 outer product of these entries
//     (validity folded into weights; entry yi=(s_y,lo/hi) x xi=(s_x,lo/hi)).
//   - Strips: 8 x 25 rows (+6 overlap = 31 staged rows, 24.8 KB LDS).
//     512-thread blocks -> 4 blocks/CU, 32 waves/CU (max occupancy).
//     Strip coverage proof: binh <= 64/7; sample rows span <= lo0(s=0)+6;
//     lo0 in [25s,25s+24] -> rows <= 25s+30, staged [25s,25s+30]. Exact.
//   - ws layout (ints): cnt[32] | lists[32][N*7] | yrows int4[N*7] |
//     yw float4[N*7] | xcols int4[N*7] | xw float4[N*7]  (~690 KB).
// Fixed harness overhead (~167us: 640MB ws poison + input restore + out
// poison) is untouchable; target kernel-sum 93 -> ~50us.

#define R_PH 7
#define R_PW 7
#define R_SR 2
#define R_SCALE 0.25f
#define R_C 256
#define R_H 200
#define R_W 200
#define R_HW (R_H * R_W)
#define STRIP 25
#define NSTRIP 8
#define NLISTS 32                 // 4 batches x 8 strips
#define STAGE_ROWS 31

__device__ __forceinline__ void axis_sample(float start, float bin, int p, int s, int size,
                                            int& lo, int& hi, float& wlo, float& whi) {
    // coord = start + p*bin + (s+0.5)*bin/SR   (same grouping as reference)
    float coord = (start + (float)p * bin) + ((float)s + 0.5f) * bin * (1.0f / R_SR);
    bool valid = (coord >= -1.0f) && (coord <= (float)size);
    float c = fmaxf(coord, 0.0f);
    int lo_raw = (int)floorf(c);
    bool at_edge = lo_raw >= size - 1;
    lo = at_edge ? size - 1 : lo_raw;
    hi = at_edge ? size - 1 : lo_raw + 1;
    float cv = at_edge ? (float)(size - 1) : c;
    float frac = cv - (float)lo;          // weight toward hi
    whi = valid ? frac : 0.0f;
    wlo = valid ? (1.0f - frac) : 0.0f;
}

// ---------- Pre-kernel: worklists + sample metadata ----------
__global__ void __launch_bounds__(512)
build_lists(const float* __restrict__ rois, int N, int* __restrict__ ws) {
    __shared__ int lcnt[NLISTS];
    int t = threadIdx.x;
    if (t < NLISTS) lcnt[t] = 0;
    __syncthreads();
    int*    lists = ws + NLISTS;
    int4*   yrows = (int4*)(lists + NLISTS * N * R_PH);
    float4* yw    = (float4*)(yrows + N * R_PH);
    int4*   xcols = (int4*)(yw + N * R_PH);
    float4* xw    = (float4*)(xcols + N * R_PH);

    for (int n = t; n < N; n += 512) {
        const float* r = rois + (size_t)n * 5;
        int b = (int)r[0];
        float sx = r[1] * R_SCALE - 0.5f;
        float sy = r[2] * R_SCALE - 0.5f;
        float ex = r[3] * R_SCALE - 0.5f;
        float ey = r[4] * R_SCALE - 0.5f;
        float binw = (ex - sx) * (1.0f / R_PW);
        float binh = (ey - sy) * (1.0f / R_PH);
        for (int p = 0; p < R_PH; ++p) {   // PH == PW == 7: one loop for both axes
            int lo0, hi0, lo1, hi1; float wl0, wh0, wl1, wh1;
            // y axis
            axis_sample(sy, binh, p, 0, R_H, lo0, hi0, wl0, wh0);
            axis_sample(sy, binh, p, 1, R_H, lo1, hi1, wl1, wh1);
            yrows[n * R_PH + p] = make_int4(lo0 * R_W, hi0 * R_W, lo1 * R_W, hi1 * R_W);
            yw[n * R_PH + p]    = make_float4(wl0 * 0.25f, wh0 * 0.25f, wl1 * 0.25f, wh1 * 0.25f);
            int bs = b * NSTRIP + lo0 / STRIP;     // lo0 (s=0) == min row touched
            int pos = atomicAdd(&lcnt[bs], 1);
            lists[bs * (N * R_PH) + pos] = (n << 3) | p;
            // x axis
            axis_sample(sx, binw, p, 0, R_W, lo0, hi0, wl0, wh0);
            axis_sample(sx, binw, p, 1, R_W, lo1, hi1, wl1, wh1);
            xcols[n * R_PH + p] = make_int4(lo0, hi0, lo1, hi1);
            xw[n * R_PH + p]    = make_float4(wl0, wh0, wl1, wh1);
        }
    }
    __syncthreads();
    if (t < NLISTS) ws[t] = lcnt[t];
}

// ---------- Main: strip-LDS gather, metadata-driven ----------
// grid (C=256, B=4, NSTRIP=8), block 512. 24.8KB LDS -> 4 blocks/CU.
__global__ void __launch_bounds__(512)
roi_strip(const float* __restrict__ input,
          const int* __restrict__ ws, int N,
          float* __restrict__ out) {
    __shared__ float pl[STAGE_ROWS * R_W];   // 24800 B
    int c = blockIdx.x;
    int b = blockIdx.y;
    int s = blockIdx.z;
    int r0 = s * STRIP;
    int nrows = min(STAGE_ROWS, R_H - r0);

    const float4* src = (const float4*)(input + (size_t)(b * R_C + c) * R_HW + r0 * R_W);
    float4* dstv = (float4*)pl;
    int nf4 = nrows * (R_W / 4);
    for (int i = threadIdx.x; i < nf4; i += 512) dstv[i] = src[i];

    int m = ws[b * NSTRIP + s];
    const int*    lists = ws + NLISTS;
    const int*    list  = lists + (b * NSTRIP + s) * (N * R_PH);
    const int4*   yrows = (const int4*)(lists + NLISTS * N * R_PH);
    const float4* yw    = (const float4*)(yrows + N * R_PH);
    const int4*   xcols = (const int4*)(yw + N * R_PH);
    const float4* xw    = (const float4*)(xcols + N * R_PH);
    __syncthreads();

    int r0b = r0 * R_W;
    int total = m * R_PW;
    for (int i = threadIdx.x; i < total; i += 512) {
        int e  = i / R_PW;
        int pw = i - e * R_PW;
        int code = list[e];
        int n  = code >> 3;
        int ph = code & 7;
        int4   yr  = yrows[n * R_PH + ph];
        float4 ywt = yw[n * R_PH + ph];
        int4   xc  = xcols[n * R_PH + pw];
        float4 xwt = xw[n * R_PH + pw];

        const float* p0 = pl + (yr.x - r0b);
        const float* p1 = pl + (yr.y - r0b);
        const float* p2 = pl + (yr.z - r0b);
        const float* p3 = pl + (yr.w - r0b);
        float s0 = xwt.x * p0[xc.x] + xwt.y * p0[xc.y] + xwt.z * p0[xc.z] + xwt.w * p0[xc.w];
        float s1 = xwt.x * p1[xc.x] + xwt.y * p1[xc.y] + xwt.z * p1[xc.z] + xwt.w * p1[xc.w];
        float s2 = xwt.x * p2[xc.x] + xwt.y * p2[xc.y] + xwt.z * p2[xc.z] + xwt.w * p2[xc.w];
        float s3 = xwt.x * p3[xc.x] + xwt.y * p3[xc.y] + xwt.z * p3[xc.z] + xwt.w * p3[xc.w];
        // 0.25 mean factor folded into ywt
        out[(size_t)(n * R_C + c) * 49 + ph * R_PW + pw] =
            ywt.x * s0 + ywt.y * s1 + ywt.z * s2 + ywt.w * s3;
    }
}

// ---------- Fallback: round-1 single-pass kernel (if ws too small) ----------
__global__ void __launch_bounds__(256)
roi_align_fwd(const float* __restrict__ input,
              const float* __restrict__ rois,
              float* __restrict__ out, int total) {
    int idx = blockIdx.x * blockDim.x + threadIdx.x;
    if (idx >= total) return;
    int pw = idx % R_PW;
    int ph = (idx / R_PW) % R_PH;
    int c  = (idx / (R_PW * R_PH)) % R_C;
    int n  = idx / (R_PW * R_PH * R_C);
    const float* r = rois + (size_t)n * 5;
    int   b  = (int)r[0];
    float sx = r[1] * R_SCALE - 0.5f;
    float sy = r[2] * R_SCALE - 0.5f;
    float ex = r[3] * R_SCALE - 0.5f;
    float ey = r[4] * R_SCALE - 0.5f;
    float bin_w = (ex - sx) * (1.0f / R_PW);
    float bin_h = (ey - sy) * (1.0f / R_PH);
    const float* plane = input + (size_t)(b * R_C + c) * R_HW;
    int   ylo[R_SR], yhi[R_SR], xlo[R_SR], xhi[R_SR];
    float wylo[R_SR], wyhi[R_SR], wxlo[R_SR], wxhi[R_SR];
#pragma unroll
    for (int s = 0; s < R_SR; ++s) {
        axis_sample(sy, bin_h, ph, s, R_H, ylo[s], yhi[s], wylo[s], wyhi[s]);
        axis_sample(sx, bin_w, pw, s, R_W, xlo[s], xhi[s], wxlo[s], wxhi[s]);
    }
    float acc = 0.0f;
#pragma unroll
    for (int ys = 0; ys < R_SR; ++ys) {
        const float* row_lo = plane + ylo[ys] * R_W;
        const float* row_hi = plane + yhi[ys] * R_W;
#pragma unroll
        for (int xs = 0; xs < R_SR; ++xs) {
            acc += wylo[ys] * (wxlo[xs] * row_lo[xlo[xs]] + wxhi[xs] * row_lo[xhi[xs]])
                 + wyhi[ys] * (wxlo[xs] * row_hi[xlo[xs]] + wxhi[xs] * row_hi[xhi[xs]]);
        }
    }
    out[idx] = acc * (1.0f / (R_SR * R_SR));
}

extern "C" void kernel_launch(void* const* d_in, const int* in_sizes, int n_in,
                              void* d_out, int out_size, void* d_ws, size_t ws_size,
                              hipStream_t stream) {
    const float* input = (const float*)d_in[0];
    const float* rois  = (const float*)d_in[1];
    float* out = (float*)d_out;
    int N = in_sizes[1] / 5;

    // ints: cnt[32] + lists[32*N*7] + yrows(4) + yw(4) + xcols(4) + xw(4) per (n,p)
    size_t ws_needed = (size_t)(NLISTS + NLISTS * N * R_PH + 16 * N * R_PH) * sizeof(int);
    if (ws_size >= ws_needed) {
        int* ws = (int*)d_ws;
        build_lists<<<1, 512, 0, stream>>>(rois, N, ws);
        dim3 grid(R_C, 4, NSTRIP);          // c, b, strip
        roi_strip<<<grid, 512, 0, stream>>>(input, ws, N, out);
    } else {
        int total = out_size;
        roi_align_fwd<<<(total + 255) / 256, 256, 0, stream>>>(input, rois, out, total);
    }
}

// Round 5
// 263.727 us; speedup vs baseline: 1.0436x; 1.0436x over previous
//
#include <hip/hip_runtime.h>

// ROIAlign forward (PH=PW=7, SCALE=0.25, SR=2, ALIGNED=true)
//   input [4,256,200,200] fp32 NCHW, rois [512,5], out [512,256,7,7] fp32
//
// Round-5: R3 strip config (proven fastest) + latency pipelining.
//   - R3 (4 strips, 56 rows, 512thr) kernel-sum 93us beat R4 (8 strips) 108us
//     despite lower occupancy -> compute-per-block / staging amortization
//     dominates, not wave count. Pipe-throughput sums give only ~30us busy
//     -> kernel is LATENCY-bound (3-deep load chain: list -> meta -> LDS).
//   - This round: (a) staging via global_load_lds width=16 (async DMA, no
//     VGPR round-trip); (b) metadata software pipeline: iter-0 meta loads
//     issue between staging DMA and the barrier; in the loop, iter k+1 meta
//     issues before iter k's LDS taps. Compute phase is pure ds_read+FMA.
//   - __launch_bounds__(512,6): cap VGPRs so LDS-allowed 3 blocks/CU holds.
//   - Strip coverage proof: binh <= 64/7 -> sample rows <= lo0(s=0)+6;
//     lo0 in [50s,50s+49] -> staged [50s,50s+55] = 56 rows. Exact.
// Fixed harness overhead ~165us (640MB ws poison + input restore + out
// poison) is untouchable; target kernel-sum 93 -> ~60us.

#define R_PH 7
#define R_PW 7
#define R_SR 2
#define R_SCALE 0.25f
#define R_C 256
#define R_H 200
#define R_W 200
#define R_HW (R_H * R_W)
#define STRIP 50
#define NSTRIP 4
#define NLISTS 16                 // 4 batches x 4 strips
#define STAGE_ROWS 56             // 56*200*4 = 44800 B LDS

__device__ __forceinline__ void axis_sample(float start, float bin, int p, int s, int size,
                                            int& lo, int& hi, float& wlo, float& whi) {
    // coord = start + p*bin + (s+0.5)*bin/SR   (same grouping as reference)
    float coord = (start + (float)p * bin) + ((float)s + 0.5f) * bin * (1.0f / R_SR);
    bool valid = (coord >= -1.0f) && (coord <= (float)size);
    float c = fmaxf(coord, 0.0f);
    int lo_raw = (int)floorf(c);
    bool at_edge = lo_raw >= size - 1;
    lo = at_edge ? size - 1 : lo_raw;
    hi = at_edge ? size - 1 : lo_raw + 1;
    float cv = at_edge ? (float)(size - 1) : c;
    float frac = cv - (float)lo;          // weight toward hi
    whi = valid ? frac : 0.0f;
    wlo = valid ? (1.0f - frac) : 0.0f;
}

// ---------- Pre-kernel: worklists + sample metadata ----------
// ws ints: cnt[16] | lists[16][N*7] | yrows int4[N*7] | yw float4[N*7]
//          | xcols int4[N*7] | xw float4[N*7]
__global__ void __launch_bounds__(512)
build_lists(const float* __restrict__ rois, int N, int* __restrict__ ws) {
    __shared__ int lcnt[NLISTS];
    int t = threadIdx.x;
    if (t < NLISTS) lcnt[t] = 0;
    __syncthreads();
    int*    lists = ws + NLISTS;
    int4*   yrows = (int4*)(lists + NLISTS * N * R_PH);
    float4* yw    = (float4*)(yrows + N * R_PH);
    int4*   xcols = (int4*)(yw + N * R_PH);
    float4* xw    = (float4*)(xcols + N * R_PH);

    for (int n = t; n < N; n += 512) {
        const float* r = rois + (size_t)n * 5;
        int b = (int)r[0];
        float sx = r[1] * R_SCALE - 0.5f;
        float sy = r[2] * R_SCALE - 0.5f;
        float ex = r[3] * R_SCALE - 0.5f;
        float ey = r[4] * R_SCALE - 0.5f;
        float binw = (ex - sx) * (1.0f / R_PW);
        float binh = (ey - sy) * (1.0f / R_PH);
        for (int p = 0; p < R_PH; ++p) {   // PH == PW: one loop for both axes
            int lo0, hi0, lo1, hi1; float wl0, wh0, wl1, wh1;
            // y axis
            axis_sample(sy, binh, p, 0, R_H, lo0, hi0, wl0, wh0);
            axis_sample(sy, binh, p, 1, R_H, lo1, hi1, wl1, wh1);
            yrows[n * R_PH + p] = make_int4(lo0 * R_W, hi0 * R_W, lo1 * R_W, hi1 * R_W);
            yw[n * R_PH + p]    = make_float4(wl0 * 0.25f, wh0 * 0.25f, wl1 * 0.25f, wh1 * 0.25f);
            int bs = b * NSTRIP + lo0 / STRIP;     // lo0 (s=0) == min row touched
            int pos = atomicAdd(&lcnt[bs], 1);
            lists[bs * (N * R_PH) + pos] = (n << 3) | p;
            // x axis
            axis_sample(sx, binw, p, 0, R_W, lo0, hi0, wl0, wh0);
            axis_sample(sx, binw, p, 1, R_W, lo1, hi1, wl1, wh1);
            xcols[n * R_PH + p] = make_int4(lo0, hi0, lo1, hi1);
            xw[n * R_PH + p]    = make_float4(wl0, wh0, wl1, wh1);
        }
    }
    __syncthreads();
    if (t < NLISTS) ws[t] = lcnt[t];
}

// ---------- Main: strip-LDS gather, async staging + meta pipeline ----------
// grid (C=256, B=4, NSTRIP=4), block 512. 44.8KB LDS -> 3 blocks/CU.
__global__ void __launch_bounds__(512, 6)
roi_strip(const float* __restrict__ input,
          const int* __restrict__ ws, int N,
          float* __restrict__ out) {
    __shared__ float pl[STAGE_ROWS * R_W];   // 44800 B
    int c = blockIdx.x;
    int b = blockIdx.y;
    int s = blockIdx.z;
    int t = threadIdx.x;
    int wave = t >> 6;
    int lane = t & 63;
    int r0 = s * STRIP;

    // ---- async staging: 2800 float4 chunks -> LDS via global_load_lds ----
    // Wave-chunk ch covers LDS float4 elems [ch*64, ch*64+64). LDS dest is
    // wave-uniform base + lane*16 (HW rule). Source clamped in-bounds for the
    // last strip (rows >= 200 stage duplicate data, never read).
    const float* src = input + (size_t)(b * R_C + c) * R_HW + r0 * R_W;
    int vmax = min(STAGE_ROWS, R_H - r0) * (R_W / 4);   // valid source float4s
    for (int ch = wave; ch < (STAGE_ROWS * R_W / 4 + 63) / 64; ch += 8) {
        int elem = ch * 64 + lane;
        if (elem < STAGE_ROWS * R_W / 4) {
            int ge = min(elem, vmax - 1);
            __builtin_amdgcn_global_load_lds(
                (const __attribute__((address_space(1))) void*)(src + ge * 4),
                (__attribute__((address_space(3))) void*)(pl + ch * 256),
                16, 0, 0);
        }
    }

    // ---- while DMA is in flight: list size + iter-0 metadata ----
    int m = ws[b * NSTRIP + s];
    const int*    lists = ws + NLISTS;
    const int*    list  = lists + (b * NSTRIP + s) * (N * R_PH);
    const int4*   yrows = (const int4*)(lists + NLISTS * N * R_PH);
    const float4* yw    = (const float4*)(yrows + N * R_PH);
    const int4*   xcols = (const int4*)(yw + N * R_PH);
    const float4* xw    = (const float4*)(xcols + N * R_PH);

    int total = m * R_PW;
    int r0b = r0 * R_W;

    int4 yr; float4 ywt; int4 xc; float4 xwt; size_t oidx;
    int i = t;
    bool have = i < total;
    if (have) {
        int e = i / R_PW, pw = i - e * R_PW;
        int code = list[e];
        int n = code >> 3, ph = code & 7;
        yr  = yrows[n * R_PH + ph];
        ywt = yw[n * R_PH + ph];
        xc  = xcols[n * R_PH + pw];
        xwt = xw[n * R_PH + pw];
        oidx = (size_t)(n * R_C + c) * 49 + ph * R_PW + pw;
    }
    __syncthreads();   // waits staging DMA (vmcnt) + barrier

    // ---- compute: rotate meta pipeline; k+1 meta issues before k's taps ----
    while (have) {
        int inext = i + 512;
        bool hnext = inext < total;
        int4 yr2; float4 ywt2; int4 xc2; float4 xwt2; size_t oidx2;
        if (hnext) {
            int e = inext / R_PW, pw = inext - e * R_PW;
            int code = list[e];
            int n = code >> 3, ph = code & 7;
            yr2  = yrows[n * R_PH + ph];
            ywt2 = yw[n * R_PH + ph];
            xc2  = xcols[n * R_PH + pw];
            xwt2 = xw[n * R_PH + pw];
            oidx2 = (size_t)(n * R_C + c) * 49 + ph * R_PW + pw;
        }
        const float* p0 = pl + (yr.x - r0b);
        const float* p1 = pl + (yr.y - r0b);
        const float* p2 = pl + (yr.z - r0b);
        const float* p3 = pl + (yr.w - r0b);
        float s0 = xwt.x * p0[xc.x] + xwt.y * p0[xc.y] + xwt.z * p0[xc.z] + xwt.w * p0[xc.w];
        float s1 = xwt.x * p1[xc.x] + xwt.y * p1[xc.y] + xwt.z * p1[xc.z] + xwt.w * p1[xc.w];
        float s2 = xwt.x * p2[xc.x] + xwt.y * p2[xc.y] + xwt.z * p2[xc.z] + xwt.w * p2[xc.w];
        float s3 = xwt.x * p3[xc.x] + xwt.y * p3[xc.y] + xwt.z * p3[xc.z] + xwt.w * p3[xc.w];
        // 0.25 mean factor folded into ywt
        out[oidx] = ywt.x * s0 + ywt.y * s1 + ywt.z * s2 + ywt.w * s3;
        yr = yr2; ywt = ywt2; xc = xc2; xwt = xwt2; oidx = oidx2;
        i = inext; have = hnext;
    }
}

// ---------- Fallback: round-1 single-pass kernel (if ws too small) ----------
__global__ void __launch_bounds__(256)
roi_align_fwd(const float* __restrict__ input,
              const float* __restrict__ rois,
              float* __restrict__ out, int total) {
    int idx = blockIdx.x * blockDim.x + threadIdx.x;
    if (idx >= total) return;
    int pw = idx % R_PW;
    int ph = (idx / R_PW) % R_PH;
    int c  = (idx / (R_PW * R_PH)) % R_C;
    int n  = idx / (R_PW * R_PH * R_C);
    const float* r = rois + (size_t)n * 5;
    int   b  = (int)r[0];
    float sx = r[1] * R_SCALE - 0.5f;
    float sy = r[2] * R_SCALE - 0.5f;
    float ex = r[3] * R_SCALE - 0.5f;
    float ey = r[4] * R_SCALE - 0.5f;
    float bin_w = (ex - sx) * (1.0f / R_PW);
    float bin_h = (ey - sy) * (1.0f / R_PH);
    const float* plane = input + (size_t)(b * R_C + c) * R_HW;
    int   ylo[R_SR], yhi[R_SR], xlo[R_SR], xhi[R_SR];
    float wylo[R_SR], wyhi[R_SR], wxlo[R_SR], wxhi[R_SR];
#pragma unroll
    for (int s = 0; s < R_SR; ++s) {
        axis_sample(sy, bin_h, ph, s, R_H, ylo[s], yhi[s], wylo[s], wyhi[s]);
        axis_sample(sx, bin_w, pw, s, R_W, xlo[s], xhi[s], wxlo[s], wxhi[s]);
    }
    float acc = 0.0f;
#pragma unroll
    for (int ys = 0; ys < R_SR; ++ys) {
        const float* row_lo = plane + ylo[ys] * R_W;
        const float* row_hi = plane + yhi[ys] * R_W;
#pragma unroll
        for (int xs = 0; xs < R_SR; ++xs) {
            acc += wylo[ys] * (wxlo[xs] * row_lo[xlo[xs]] + wxhi[xs] * row_lo[xhi[xs]])
                 + wyhi[ys] * (wxlo[xs] * row_hi[xlo[xs]] + wxhi[xs] * row_hi[xhi[xs]]);
        }
    }
    out[idx] = acc * (1.0f / (R_SR * R_SR));
}

extern "C" void kernel_launch(void* const* d_in, const int* in_sizes, int n_in,
                              void* d_out, int out_size, void* d_ws, size_t ws_size,
                              hipStream_t stream) {
    const float* input = (const float*)d_in[0];
    const float* rois  = (const float*)d_in[1];
    float* out = (float*)d_out;
    int N = in_sizes[1] / 5;

    // ints: cnt[16] + lists[16*N*7] + meta 16 ints per (n,p)
    size_t ws_needed = (size_t)(NLISTS + NLISTS * N * R_PH + 16 * N * R_PH) * sizeof(int);
    if (ws_size >= ws_needed) {
        int* ws = (int*)d_ws;
        build_lists<<<1, 512, 0, stream>>>(rois, N, ws);
        dim3 grid(R_C, 4, NSTRIP);          // c, b, strip
        roi_strip<<<grid, 512, 0, stream>>>(input, ws, N, out);
    } else {
        int total = out_size;
        roi_align_fwd<<<(total + 255) / 256, 256, 0, stream>>>(input, rois, out, total);
    }
}